// Round 1
// 119.122 us; speedup vs baseline: 1.0342x; 1.0342x over previous
//
#include <hip/hip_runtime.h>
#include <hip/hip_bf16.h>

// BiLingual embedding-bag-sum, R6: halve divergent-VMEM instruction count.
//   out[t,b,d] = sum_s emb_t[idx_t[b,s], d]   (B=4096, S=200, D=64, vocab=100K)
//
// Evidence R2 (fp32, 2 lines/row, no converts, 409600 gather instrs) ~= R5
// (bf16, 1 line/row, +13us converts, 409600 gather instrs) ~= 123 us:
// halving bytes/lines bought ~nothing -> cost tracks the count of divergent
// vector-load INSTRUCTIONS (~160 cyc/instr/CU in TA/TCP address processing),
// not bytes. Lever: dwordx4 gathers (16 B/lane, 8 lanes/row) fetch 8 rows
// per wave-instruction instead of 4 -> 204800 instrs total (2x fewer).
// Also merged: one convert kernel (both tables), one gather kernel (both
// tables, 2048 blocks) -> fewer graph nodes + gather visible in rocprof.
// bf16 error unchanged: <=2e-5/elem, absmax ~2e-3 < 7.6e-3 threshold.

#define BB 4096
#define SS 200
#define DD 64
#define VOCAB 100000

// ---- both tables fp32 -> packed bf16 (RTNE), streaming ----
__global__ __launch_bounds__(256) void convert_bf16_2(
    const float* __restrict__ src0, const float* __restrict__ src1,
    uint2* __restrict__ dst0, uint2* __restrict__ dst1)
{
    const unsigned NT = (unsigned)VOCAB * DD / 4;          // 1.6M float4/table
    unsigned g = blockIdx.x * 256u + threadIdx.x;          // < 3.2M
    const float* __restrict__ src = src0;
    uint2* __restrict__ dst = dst0;
    if (g >= NT) { g -= NT; src = src1; dst = dst1; }
    const float4 v = ((const float4*)src)[g];
    const unsigned u0 = __bfloat16_as_ushort(__float2bfloat16(v.x));
    const unsigned u1 = __bfloat16_as_ushort(__float2bfloat16(v.y));
    const unsigned u2 = __bfloat16_as_ushort(__float2bfloat16(v.z));
    const unsigned u3 = __bfloat16_as_ushort(__float2bfloat16(v.w));
    uint2 o;
    o.x = u0 | (u1 << 16);
    o.y = u2 | (u3 << 16);
    dst[g] = o;
}

// ---- gather-sum over bf16 rows, dwordx4 (8 rows per wave-instruction) ----
// Block = 4 waves = 4 bags. Wave: 200 tokens = 25 iters x 8 rows.
// Lane (g,l8): g = lane>>3 picks token s = 8k+g, l8 = lane&7 reads 16 B
// (elems l8*8 .. l8*8+7) of that row. 8 fp32 accumulators per lane.
// Final: shfl_down reduce across the 8 token-groups -> lanes 0..7 hold the
// 64-elem bag sum, 2x float4 store each.
__global__ __launch_bounds__(256) void embed_sum_bf16_x4(
    const int* __restrict__ idx_pri, const int* __restrict__ idx_sec,
    const uint4* __restrict__ tbl_pri, const uint4* __restrict__ tbl_sec,
    float* __restrict__ out)
{
    __shared__ int sidx[4][SS];

    const int tid  = (int)threadIdx.x;
    const int w    = tid >> 6;
    const int lane = tid & 63;
    const int blk  = (int)blockIdx.x;     // 0..2047
    const int t    = blk >> 10;           // table select (1024 blocks each)
    const int bi   = blk & 1023;          // block within table

    const int*   __restrict__ idx = t ? idx_sec : idx_pri;
    const uint4* __restrict__ tbl = t ? tbl_sec : tbl_pri;

    // Stage 4 bags of indices: 800 ints = 200 int4 loads, lanes 0..199.
    const int* ib = idx + (size_t)bi * 4 * SS;             // 3200B aligned
    if (tid < (4 * SS) / 4) {
        const int4 v = ((const int4*)ib)[tid];
        int* s = &sidx[0][0];
        s[tid * 4 + 0] = v.x;
        s[tid * 4 + 1] = v.y;
        s[tid * 4 + 2] = v.z;
        s[tid * 4 + 3] = v.w;
    }
    __syncthreads();

    const int g  = lane >> 3;
    const int l8 = lane & 7;

    float a0 = 0.f, a1 = 0.f, a2 = 0.f, a3 = 0.f;
    float a4 = 0.f, a5 = 0.f, a6 = 0.f, a7 = 0.f;

    #pragma unroll 5
    for (int k = 0; k < 25; ++k) {
        const int i = sidx[w][8 * k + g];                  // 8-way LDS bcast
        const uint4 v = tbl[(unsigned)i * 8u + l8];        // 16B: bf16 x8
        a0 += __uint_as_float(v.x << 16);
        a1 += __uint_as_float(v.x & 0xffff0000u);
        a2 += __uint_as_float(v.y << 16);
        a3 += __uint_as_float(v.y & 0xffff0000u);
        a4 += __uint_as_float(v.z << 16);
        a5 += __uint_as_float(v.z & 0xffff0000u);
        a6 += __uint_as_float(v.w << 16);
        a7 += __uint_as_float(v.w & 0xffff0000u);
    }

    // Reduce across the 8 token-groups (g): lanes g*8+l8 -> g=0 lanes 0..7.
    a0 += __shfl_down(a0, 32); a1 += __shfl_down(a1, 32);
    a2 += __shfl_down(a2, 32); a3 += __shfl_down(a3, 32);
    a4 += __shfl_down(a4, 32); a5 += __shfl_down(a5, 32);
    a6 += __shfl_down(a6, 32); a7 += __shfl_down(a7, 32);
    a0 += __shfl_down(a0, 16); a1 += __shfl_down(a1, 16);
    a2 += __shfl_down(a2, 16); a3 += __shfl_down(a3, 16);
    a4 += __shfl_down(a4, 16); a5 += __shfl_down(a5, 16);
    a6 += __shfl_down(a6, 16); a7 += __shfl_down(a7, 16);
    a0 += __shfl_down(a0, 8);  a1 += __shfl_down(a1, 8);
    a2 += __shfl_down(a2, 8);  a3 += __shfl_down(a3, 8);
    a4 += __shfl_down(a4, 8);  a5 += __shfl_down(a5, 8);
    a6 += __shfl_down(a6, 8);  a7 += __shfl_down(a7, 8);

    if (g == 0) {
        const int b = bi * 4 + w;
        float* outp = out + (size_t)t * BB * DD + (size_t)b * DD + l8 * 8;
        float4 lo; lo.x = a0; lo.y = a1; lo.z = a2; lo.w = a3;
        float4 hi; hi.x = a4; hi.y = a5; hi.z = a6; hi.w = a7;
        ((float4*)outp)[0] = lo;
        ((float4*)outp)[1] = hi;
    }
}

// ---- fallback (R2): fp32 monolithic, if ws too small ----
__global__ __launch_bounds__(256) void bilingual_embed_sum(
    const int* __restrict__ idx_pri,
    const int* __restrict__ idx_sec,
    const float* __restrict__ emb_pri,
    const float* __restrict__ emb_sec,
    float* __restrict__ out)
{
    __shared__ int sidx[4][SS];
    const int w    = (int)(threadIdx.x >> 6);
    const int lane = (int)(threadIdx.x & 63);
    const int wave = (int)(blockIdx.x * 4 + w);
    const int table = wave >> 12;
    const int b     = wave & (BB - 1);

    const int*   idx = table ? idx_sec : idx_pri;
    const float* emb = table ? emb_sec : emb_pri;
    float* outp = out + (size_t)table * BB * DD + (size_t)b * DD;

    const int* row_idx = idx + b * SS;
    if (lane < SS / 4) {
        const int4 v = ((const int4*)row_idx)[lane];
        sidx[w][lane * 4 + 0] = v.x;
        sidx[w][lane * 4 + 1] = v.y;
        sidx[w][lane * 4 + 2] = v.z;
        sidx[w][lane * 4 + 3] = v.w;
    }
    __syncthreads();

    const int q   = lane >> 4;
    const int l16 = lane & 15;
    float4 acc = make_float4(0.f, 0.f, 0.f, 0.f);

    #pragma unroll 10
    for (int s0 = 0; s0 < SS; s0 += 4) {
        const int i = sidx[w][s0 + q];
        const float4 v = ((const float4*)(emb + (size_t)i * DD))[l16];
        acc.x += v.x; acc.y += v.y; acc.z += v.z; acc.w += v.w;
    }

    acc.x += __shfl_down(acc.x, 32);
    acc.y += __shfl_down(acc.y, 32);
    acc.z += __shfl_down(acc.z, 32);
    acc.w += __shfl_down(acc.w, 32);
    acc.x += __shfl_down(acc.x, 16);
    acc.y += __shfl_down(acc.y, 16);
    acc.z += __shfl_down(acc.z, 16);
    acc.w += __shfl_down(acc.w, 16);

    if (lane < 16) ((float4*)outp)[l16] = acc;
}

extern "C" void kernel_launch(void* const* d_in, const int* in_sizes, int n_in,
                              void* d_out, int out_size, void* d_ws, size_t ws_size,
                              hipStream_t stream) {
    const int*   idx_pri = (const int*)d_in[0];
    const int*   idx_sec = (const int*)d_in[1];
    const float* emb_pri = (const float*)d_in[2];
    const float* emb_sec = (const float*)d_in[3];
    float* out = (float*)d_out;

    const size_t tbl_u2 = (size_t)VOCAB * DD / 4;        // uint2 per table
    const size_t ws_need = tbl_u2 * 8 * 2;               // 25.6 MB (both bf16)

    if (ws_size >= ws_need) {
        uint2* t0 = (uint2*)d_ws;
        uint2* t1 = t0 + tbl_u2;
        const int conv_grid   = (2 * VOCAB * DD / 4) / 256;  // 12500
        const int gather_grid = 2 * (BB / 4);                // 2048

        convert_bf16_2<<<conv_grid, 256, 0, stream>>>(emb_pri, emb_sec, t0, t1);
        embed_sum_bf16_x4<<<gather_grid, 256, 0, stream>>>(
            idx_pri, idx_sec, (const uint4*)t0, (const uint4*)t1, out);
    } else {
        bilingual_embed_sum<<<(2 * BB) / 4, 256, 0, stream>>>(
            idx_pri, idx_sec, emb_pri, emb_sec, out);
    }
}